// Round 4
// baseline (864.513 us; speedup 1.0000x reference)
//
#include <hip/hip_runtime.h>
#include <cmath>

// UOT Bregman ADMM (badmm-e), B=64, N=1024, D=512, NUM=4 iterations. f32.
//
// Separable-marginal algebra (verified R2/R3): log_mu is (B,D)-only,
// log_eta is (B,N)-only; z1/z2 broadcast parts cancel under normalization.
//
// Round-4: fuse step-S(k) + step-T(k+1) into one row-kernel `fuse`.
// Per iteration only ONE round trip of the big tensors:
//   P0:  R x           -> W y'_0 + partials
//   F_k: R x,y'_k,z    -> W y'_{k+1}, z_k + partials   (k=0: no z read)
//   F_2: R x,y'_2,z    -> W out only
// Column-lse stays a kernel boundary (kred). log_eta double-buffered
// (small<k> writes len_k while F_k reads len_{k-1}).
// 16 rows per wave, register column-partials, 2-row ping-pong prefetch.

#define B_ 64
#define N_ 1024
#define D_ 512
#define EPS_ 1e-8f
#define NCOL (B_ * D_)        // 32768 (b,d) columns
#define KCHUNK 64             // N/16 row-chunks
static const size_t NT_ = (size_t)B_ * N_ * D_;

__device__ __forceinline__ float wmax64(float v) {
#pragma unroll
  for (int o = 32; o > 0; o >>= 1) v = fmaxf(v, __shfl_xor(v, o, 64));
  return v;
}
__device__ __forceinline__ float wsum64(float v) {
#pragma unroll
  for (int o = 32; o > 0; o >>= 1) v += __shfl_xor(v, o, 64);
  return v;
}
__device__ __forceinline__ void olse(float& m, float& s, float v) {
  float nm = fmaxf(m, v);
  s = s * __expf(m - nm) + __expf(v - nm);
  m = nm;
}

// ---------------------------------------------------------------------------
// P0: step-T at k=0. One wave per 16-row chunk, 8 cols/lane.
// y = x/rho0 + log(q0*p0+eps); row-lse; y'_0 = (log(p0)-lse+y)*rho0/(a1+rho0).
// Column partials (max,sumexp over 16 rows) kept in registers.
// ---------------------------------------------------------------------------
__global__ __launch_bounds__(256, 4) void p0k(
    const float* __restrict__ x, const float* __restrict__ p0,
    const float* __restrict__ q0,
    const float* __restrict__ a1arr, const float* __restrict__ rhoarr,
    float* __restrict__ ys, float* __restrict__ pmax, float* __restrict__ psum)
{
  const int wid = threadIdx.x >> 6, lane = threadIdx.x & 63;
  const int chunk = blockIdx.x * 4 + wid;       // [0, 4096)
  const int b = chunk >> 6, cb = chunk & 63;
  const int c0 = lane * 8;
  const int row0 = chunk * 16;
  const float rho0 = rhoarr[0];
  const float ir = 1.0f / rho0;
  const float w0 = rho0 / (a1arr[0] + rho0);
  float pv[8], lp[8];
  *(float4*)&pv[0] = *(const float4*)&p0[(b << 9) + c0];
  *(float4*)&pv[4] = *(const float4*)&p0[(b << 9) + c0 + 4];
#pragma unroll
  for (int j = 0; j < 8; ++j) lp[j] = __logf(pv[j]);
  float m[8], s[8];
#pragma unroll
  for (int j = 0; j < 8; ++j) { m[j] = -INFINITY; s[j] = 0.f; }
  const size_t base0 = (size_t)row0 * D_ + c0;

  float xA[8], xB[8];
  float qA, qB;

#define LOADP(X, Q, r) do {                                   \
    const size_t o_ = base0 + (size_t)(r) * D_;               \
    *(float4*)&X[0] = *(const float4*)&x[o_];                 \
    *(float4*)&X[4] = *(const float4*)&x[o_ + 4];             \
    Q = q0[row0 + (r)];                                       \
  } while (0)

#define PROCP(X, Q, r) do {                                   \
    _Pragma("unroll")                                         \
    for (int j = 0; j < 8; ++j)                               \
      X[j] = X[j] * ir + __logf(Q * pv[j] + EPS_);            \
    float mm_ = -INFINITY;                                    \
    _Pragma("unroll")                                         \
    for (int j = 0; j < 8; ++j) mm_ = fmaxf(mm_, X[j]);       \
    mm_ = wmax64(mm_);                                        \
    float ss_ = 0.f;                                          \
    _Pragma("unroll")                                         \
    for (int j = 0; j < 8; ++j) ss_ += __expf(X[j] - mm_);    \
    const float lse_ = mm_ + __logf(wsum64(ss_));             \
    float yp_[8];                                             \
    _Pragma("unroll")                                         \
    for (int j = 0; j < 8; ++j)                               \
      yp_[j] = (lp[j] - lse_ + X[j]) * w0;                    \
    const size_t o_ = base0 + (size_t)(r) * D_;               \
    *(float4*)&ys[o_]     = *(float4*)&yp_[0];                \
    *(float4*)&ys[o_ + 4] = *(float4*)&yp_[4];                \
    _Pragma("unroll")                                         \
    for (int j = 0; j < 8; ++j) olse(m[j], s[j], yp_[j]);     \
  } while (0)

  LOADP(xA, qA, 0);
#pragma unroll
  for (int rr = 0; rr < 16; rr += 2) {
    LOADP(xB, qB, rr + 1);
    PROCP(xA, qA, rr);
    if (rr + 2 < 16) LOADP(xA, qA, rr + 2);
    PROCP(xB, qB, rr + 1);
  }
#undef LOADP
#undef PROCP
  const int pcol = cb * NCOL + (b << 9) + c0;
  *(float4*)&pmax[pcol]     = *(float4*)&m[0];
  *(float4*)&pmax[pcol + 4] = *(float4*)&m[4];
  *(float4*)&psum[pcol]     = *(float4*)&s[0];
  *(float4*)&psum[pcol + 4] = *(float4*)&s[4];
}

// ---------------------------------------------------------------------------
// fuse<IS_FIRST,LAST>: step-S(k) + step-T(k+1), one wave per 16-row chunk.
//   ls  = (log_eta_{k-1} - lse1) + y'_k
//   lt  = (y'_k*(a1+rho) - z_{k-1})/rho        (exact log_t reconstruction)
//   z_k = z_{k-1} + rho*(exp(lt)-exp(ls))*mask
//   y   = (x - z_k)/rho_{k+1} + ls;  row-lse
//   LAST: out = exp(mun - lse + y)*mask
//   else: y'_{k+1} = (z_k + rho_{k+1}(mun - lse + y))/(a1_{k+1}+rho_{k+1})
// ---------------------------------------------------------------------------
template <int IS_FIRST, int LAST>
__global__ __launch_bounds__(256, 4) void fuse(
    const float* __restrict__ x, const float* __restrict__ q0,
    const float* __restrict__ mask,
    const float* __restrict__ a1arr, const float* __restrict__ rhoarr,
    const int k, const float* __restrict__ lse1,
    const float* __restrict__ lenR, const float* __restrict__ mun,
    float* __restrict__ ys, float* __restrict__ zbuf,
    float* __restrict__ pmax, float* __restrict__ psum,
    float* __restrict__ outv)
{
  const int wid = threadIdx.x >> 6, lane = threadIdx.x & 63;
  const int chunk = blockIdx.x * 4 + wid;
  const int b = chunk >> 6, cb = chunk & 63;
  const int c0 = lane * 8;
  const int row0 = chunk * 16;
  const float rhok = rhoarr[k];
  const float sck = a1arr[k] + rhok;
  const float irk = 1.0f / rhok;
  const float rhon = rhoarr[k + 1];
  const float irn = 1.0f / rhon;
  const float iscn = 1.0f / (a1arr[k + 1] + rhon);
  const size_t base0 = (size_t)row0 * D_ + c0;

  float L[8], lm[8];
  *(float4*)&L[0]  = *(const float4*)&lse1[(b << 9) + c0];
  *(float4*)&L[4]  = *(const float4*)&lse1[(b << 9) + c0 + 4];
  *(float4*)&lm[0] = *(const float4*)&mun[(b << 9) + c0];
  *(float4*)&lm[4] = *(const float4*)&mun[(b << 9) + c0 + 4];
  float m[8], s[8];
#pragma unroll
  for (int j = 0; j < 8; ++j) { m[j] = -INFINITY; s[j] = 0.f; }

  float xA[8], pA[8], zA[8], xB[8], pB[8], zB[8];
  float leA, mvA, leB, mvB;

#define LOADF(X, P, Z, LE, MV, r) do {                        \
    const size_t o_ = base0 + (size_t)(r) * D_;               \
    *(float4*)&X[0] = *(const float4*)&x[o_];                 \
    *(float4*)&X[4] = *(const float4*)&x[o_ + 4];             \
    *(float4*)&P[0] = *(const float4*)&ys[o_];                \
    *(float4*)&P[4] = *(const float4*)&ys[o_ + 4];            \
    if (!IS_FIRST) {                                          \
      *(float4*)&Z[0] = *(const float4*)&zbuf[o_];            \
      *(float4*)&Z[4] = *(const float4*)&zbuf[o_ + 4];        \
    }                                                         \
    LE = IS_FIRST ? __logf(q0[row0 + (r)] + EPS_)             \
                  : lenR[row0 + (r)];                         \
    MV = mask[row0 + (r)];                                    \
  } while (0)

#define PROCF(X, P, Z, LE, MV, r) do {                        \
    float ls_[8];                                             \
    _Pragma("unroll")                                         \
    for (int j = 0; j < 8; ++j) {                             \
      ls_[j] = (LE - L[j]) + P[j];                            \
      float lt_ = IS_FIRST ? P[j] * sck * irk                 \
                           : (P[j] * sck - Z[j]) * irk;       \
      float zn_ = (IS_FIRST ? 0.f : Z[j]) +                   \
                  rhok * MV * (__expf(lt_) - __expf(ls_[j])); \
      Z[j] = zn_;                                             \
      X[j] = (X[j] - zn_) * irn + ls_[j];                     \
    }                                                         \
    float mm_ = -INFINITY;                                    \
    _Pragma("unroll")                                         \
    for (int j = 0; j < 8; ++j) mm_ = fmaxf(mm_, X[j]);       \
    mm_ = wmax64(mm_);                                        \
    float ss_ = 0.f;                                          \
    _Pragma("unroll")                                         \
    for (int j = 0; j < 8; ++j) ss_ += __expf(X[j] - mm_);    \
    const float lse_ = mm_ + __logf(wsum64(ss_));             \
    const size_t o_ = base0 + (size_t)(r) * D_;               \
    if (LAST) {                                               \
      float ov_[8];                                           \
      _Pragma("unroll")                                       \
      for (int j = 0; j < 8; ++j)                             \
        ov_[j] = __expf(lm[j] - lse_ + X[j]) * MV;            \
      *(float4*)&outv[o_]     = *(float4*)&ov_[0];            \
      *(float4*)&outv[o_ + 4] = *(float4*)&ov_[4];            \
    } else {                                                  \
      _Pragma("unroll")                                       \
      for (int j = 0; j < 8; ++j)                             \
        ls_[j] = (Z[j] + rhon * (lm[j] - lse_ + X[j])) * iscn;\
      *(float4*)&ys[o_]       = *(float4*)&ls_[0];            \
      *(float4*)&ys[o_ + 4]   = *(float4*)&ls_[4];            \
      *(float4*)&zbuf[o_]     = *(float4*)&Z[0];              \
      *(float4*)&zbuf[o_ + 4] = *(float4*)&Z[4];              \
      _Pragma("unroll")                                       \
      for (int j = 0; j < 8; ++j) olse(m[j], s[j], ls_[j]);   \
    }                                                         \
  } while (0)

  LOADF(xA, pA, zA, leA, mvA, 0);
#pragma unroll
  for (int rr = 0; rr < 16; rr += 2) {
    LOADF(xB, pB, zB, leB, mvB, rr + 1);
    PROCF(xA, pA, zA, leA, mvA, rr);
    if (rr + 2 < 16) LOADF(xA, pA, zA, leA, mvA, rr + 2);
    PROCF(xB, pB, zB, leB, mvB, rr + 1);
  }
#undef LOADF
#undef PROCF

  if (!LAST) {
    const int pcol = cb * NCOL + (b << 9) + c0;
    *(float4*)&pmax[pcol]     = *(float4*)&m[0];
    *(float4*)&pmax[pcol + 4] = *(float4*)&m[4];
    *(float4*)&psum[pcol]     = *(float4*)&s[0];
    *(float4*)&psum[pcol + 4] = *(float4*)&s[4];
  }
}

// ---------------------------------------------------------------------------
// kred: combine 64 chunk partials per column -> lse1[NCOL].
// ---------------------------------------------------------------------------
__global__ __launch_bounds__(256) void kred(
    const float* __restrict__ pmax, const float* __restrict__ psum,
    float* __restrict__ lse1)
{
  const int col = blockIdx.x * 256 + threadIdx.x;
  float m0 = -INFINITY, m1 = -INFINITY, m2 = -INFINITY, m3 = -INFINITY;
#pragma unroll
  for (int c = 0; c < KCHUNK; c += 4) {
    m0 = fmaxf(m0, pmax[(c + 0) * NCOL + col]);
    m1 = fmaxf(m1, pmax[(c + 1) * NCOL + col]);
    m2 = fmaxf(m2, pmax[(c + 2) * NCOL + col]);
    m3 = fmaxf(m3, pmax[(c + 3) * NCOL + col]);
  }
  const float M = fmaxf(fmaxf(m0, m1), fmaxf(m2, m3));
  float s0 = 0.f, s1 = 0.f, s2 = 0.f, s3 = 0.f;
#pragma unroll
  for (int c = 0; c < KCHUNK; c += 4) {
    s0 += psum[(c + 0) * NCOL + col] * __expf(pmax[(c + 0) * NCOL + col] - M);
    s1 += psum[(c + 1) * NCOL + col] * __expf(pmax[(c + 1) * NCOL + col] - M);
    s2 += psum[(c + 2) * NCOL + col] * __expf(pmax[(c + 2) * NCOL + col] - M);
    s3 += psum[(c + 3) * NCOL + col] * __expf(pmax[(c + 3) * NCOL + col] - M);
  }
  lse1[col] = M + __logf((s0 + s1) + (s2 + s3));
}

// ---------------------------------------------------------------------------
// small: marginal updates (tiny). blockIdx.y=0: mu (lse over D);
// blockIdx.y=1: eta (lse over N). len double-buffered: reads lenR, writes lenW.
// ---------------------------------------------------------------------------
template <int K>
__global__ __launch_bounds__(256) void small_upd(
    const float* __restrict__ p0, const float* __restrict__ q0,
    const float* __restrict__ a2arr, const float* __restrict__ a3arr,
    const float* __restrict__ rhoarr,
    float* mun, float* zC, const float* __restrict__ lenR,
    float* lenW, float* z2C)
{
  __shared__ float red[8];
  const int b = blockIdx.x;
  const int tid = threadIdx.x, wid = tid >> 6, lane = tid & 63;
  const float rho = rhoarr[K];

  if (blockIdx.y == 0) {
    const float a2 = a2arr[K];
    const float inv = 1.0f / (rho + a2);
    float A[2], zcv[2];
    const int i0 = b * D_ + tid;
#pragma unroll
    for (int j = 0; j < 2; ++j) {
      int i = i0 + j * 256;
      float lp = __logf(p0[i]);
      float prev = (K == 0) ? lp : mun[i];
      zcv[j] = (K == 0) ? 0.f : zC[i];
      A[j] = (rho * prev + a2 * lp - zcv[j]) * inv;
    }
    float m = wmax64(fmaxf(A[0], A[1]));
    if (lane == 0) red[wid] = m;
    __syncthreads();
    float bm = fmaxf(fmaxf(red[0], red[1]), fmaxf(red[2], red[3]));
    float s = wsum64(__expf(A[0] - bm) + __expf(A[1] - bm));
    if (lane == 0) red[4 + wid] = s;
    __syncthreads();
    float lse = bm + __logf(red[4] + red[5] + red[6] + red[7]);
#pragma unroll
    for (int j = 0; j < 2; ++j) {
      int i = i0 + j * 256;
      float mn = A[j] - lse;
      mun[i] = mn;
      if (K <= 1) zC[i] = zcv[j] + rho * __expf(mn);
    }
  } else {
    const float a3 = a3arr[K];
    const float inv = 1.0f / (rho + a3);
    float E[4];
    const int i0 = b * N_ + tid * 4;
#pragma unroll
    for (int j = 0; j < 4; ++j) {
      int i = i0 + j;
      float lq = __logf(q0[i] + EPS_);
      float prev = (K == 0) ? lq : lenR[i];
      float z2c = (K == 0) ? 0.f : z2C[i];
      E[j] = (rho * prev + a3 * lq - z2c) * inv;
    }
    float m = wmax64(fmaxf(fmaxf(E[0], E[1]), fmaxf(E[2], E[3])));
    if (lane == 0) red[wid] = m;
    __syncthreads();
    float bm = fmaxf(fmaxf(red[0], red[1]), fmaxf(red[2], red[3]));
    float s = 0.f;
#pragma unroll
    for (int j = 0; j < 4; ++j) s += __expf(E[j] - bm);
    s = wsum64(s);
    if (lane == 0) red[4 + wid] = s;
    __syncthreads();
    float lse = bm + __logf(red[4] + red[5] + red[6] + red[7]);
#pragma unroll
    for (int j = 0; j < 4; ++j) {
      int i = i0 + j;
      float ln = E[j] - lse;
      lenW[i] = ln;
      if (K == 0) z2C[i] = rho * __expf(ln);
    }
  }
}

// ---------------------------------------------------------------------------
extern "C" void kernel_launch(void* const* d_in, const int* in_sizes, int n_in,
                              void* d_out, int out_size, void* d_ws, size_t ws_size,
                              hipStream_t stream)
{
  const float* x    = (const float*)d_in[0];
  const float* p0   = (const float*)d_in[1];
  const float* q0   = (const float*)d_in[2];
  const float* a1   = (const float*)d_in[3];
  const float* a2   = (const float*)d_in[4];
  const float* a3   = (const float*)d_in[5];
  const float* rho  = (const float*)d_in[6];
  const float* mask = (const float*)d_in[7];
  float* out = (float*)d_out;

  float* ws   = (float*)d_ws;
  float* ys   = ws;                               // y' (B,N,D)
  float* z    = ws + NT_;                         // z  (B,N,D)
  float* pmax = ws + 2 * NT_;                     // (KCHUNK, NCOL)
  float* psum = pmax + (size_t)KCHUNK * NCOL;
  float* lse1 = psum + (size_t)KCHUNK * NCOL;     // (NCOL)
  float* mun  = lse1 + NCOL;                      // log_mu (B,D)
  float* zC   = mun  + NCOL;                      // z1 col part (B,D)
  float* lenA = zC   + NCOL;                      // log_eta buf A (B,N)
  float* lenB = lenA + (size_t)B_ * N_;           // log_eta buf B (B,N)
  float* z2C  = lenB + (size_t)B_ * N_;           // z2 row part (B,N)

  const dim3 tb(256);
  const dim3 gBig(B_ * N_ / 16 / 4);              // 1024 blocks, 4 waves each
  const dim3 gr(NCOL / 256);                      // 128 blocks

  // k=0 step T
  p0k<<<gBig, tb, 0, stream>>>(x, p0, q0, a1, rho, ys, pmax, psum);
  kred<<<gr, tb, 0, stream>>>(pmax, psum, lse1);
  small_upd<0><<<dim3(B_, 2), tb, 0, stream>>>(p0, q0, a2, a3, rho,
                                               mun, zC, lenA, lenA, z2C);
  // F0: step S(0) + step T(1); len_{-1} from q0 in-kernel; needs mun_0
  fuse<1, 0><<<gBig, tb, 0, stream>>>(x, q0, mask, a1, rho, 0, lse1,
                                      lenA, mun, ys, z, pmax, psum, out);
  kred<<<gr, tb, 0, stream>>>(pmax, psum, lse1);
  small_upd<1><<<dim3(B_, 2), tb, 0, stream>>>(p0, q0, a2, a3, rho,
                                               mun, zC, lenA, lenB, z2C);
  // F1: step S(1) + step T(2); reads len_0 (lenA), mun_1
  fuse<0, 0><<<gBig, tb, 0, stream>>>(x, q0, mask, a1, rho, 1, lse1,
                                      lenA, mun, ys, z, pmax, psum, out);
  kred<<<gr, tb, 0, stream>>>(pmax, psum, lse1);
  small_upd<2><<<dim3(B_, 1), tb, 0, stream>>>(p0, q0, a2, a3, rho,
                                               mun, zC, lenB, lenB, z2C);
  // F2: step S(2) + step T(3) -> out; reads len_1 (lenB), mun_2
  fuse<0, 1><<<gBig, tb, 0, stream>>>(x, q0, mask, a1, rho, 2, lse1,
                                      lenB, mun, ys, z, pmax, psum, out);
}